// Round 5
// baseline (154.701 us; speedup 1.0000x reference)
//
#include <hip/hip_runtime.h>

typedef float  f32x4  __attribute__((ext_vector_type(4)));
typedef float  f32x16 __attribute__((ext_vector_type(16)));
typedef __bf16 bf16x8 __attribute__((ext_vector_type(8)));
typedef short  s16x8  __attribute__((ext_vector_type(8)));
typedef short  s16x4  __attribute__((ext_vector_type(4)));
typedef unsigned int u32x4 __attribute__((ext_vector_type(4)));

static __device__ __forceinline__ unsigned short f2bf(float f) {
  return __builtin_bit_cast(unsigned short, (__bf16)f);
}
static __device__ __forceinline__ bf16x8 bc8(s16x8 v) {
  return __builtin_bit_cast(bf16x8, v);
}
static __device__ __forceinline__ f32x16 mfma32(bf16x8 a, bf16x8 b, f32x16 c) {
  return __builtin_amdgcn_mfma_f32_32x32x16_bf16(a, b, c, 0, 0, 0);
}
static __device__ __forceinline__ unsigned pack2(float a, float b) {
  return ((unsigned)f2bf(b) << 16) | f2bf(a);
}

// async global->LDS, 16B per lane.
static __device__ __forceinline__ void gl2lds16(const unsigned short* g, unsigned short* l) {
  __builtin_amdgcn_global_load_lds(
      (const __attribute__((address_space(1))) unsigned int*)g,
      (__attribute__((address_space(3))) unsigned int*)l, 16, 0, 0);
}

// ---------------- cast x (fp32 -> bf16) ----------------
__global__ void cast_x_k(const float* __restrict__ x, unsigned short* __restrict__ xb) {
  int i = (blockIdx.x * 256 + threadIdx.x) * 8;
  float4 a = *(const float4*)(x + i);
  float4 b = *(const float4*)(x + i + 4);
  s16x8 o;
  o[0] = (short)f2bf(a.x); o[1] = (short)f2bf(a.y);
  o[2] = (short)f2bf(a.z); o[3] = (short)f2bf(a.w);
  o[4] = (short)f2bf(b.x); o[5] = (short)f2bf(b.y);
  o[6] = (short)f2bf(b.z); o[7] = (short)f2bf(b.w);
  *(s16x8*)(xb + i) = o;
}

// ------------- transpose W (1024x1024 fp32 k-major) -> WT bf16 (n-major) -------------
__global__ void transpose_w_k(const float* __restrict__ W0, const float* __restrict__ W1,
                              const float* __restrict__ W2, const float* __restrict__ W3,
                              unsigned short* __restrict__ wtb) {
  const float* W = blockIdx.z == 0 ? W0 : blockIdx.z == 1 ? W1 : blockIdx.z == 2 ? W2 : W3;
  unsigned short* out = wtb + (size_t)blockIdx.z * 1048576;
  __shared__ unsigned short tl[64][72];
  const int t = threadIdx.x;
  const int kt = blockIdx.y * 64, nt = blockIdx.x * 64;
  const int row = t >> 2, seg = t & 3;
  const float* src = W + (kt + row) * 1024 + nt + seg * 16;
#pragma unroll
  for (int q = 0; q < 4; ++q) {
    float4 v = *(const float4*)(src + q * 4);
    tl[seg * 16 + q * 4 + 0][row] = f2bf(v.x);
    tl[seg * 16 + q * 4 + 1][row] = f2bf(v.y);
    tl[seg * 16 + q * 4 + 2][row] = f2bf(v.z);
    tl[seg * 16 + q * 4 + 3][row] = f2bf(v.w);
  }
  __syncthreads();
  unsigned short* dst = out + (nt + row) * 1024 + kt + seg * 16;
  *(s16x8*)dst       = *(const s16x8*)&tl[row][seg * 16];
  *(s16x8*)(dst + 8) = *(const s16x8*)&tl[row][seg * 16 + 8];
}

static __device__ __forceinline__ int trans_ix(int m, int n) {
  int b = m >> 11, tt = m & 2047, h = n >> 6, dh = n & 63;
  return ((b << 4) + h) * 131072 + tt * 64 + dh;
}

// ---------------- GEMM (m97 structure): C(4096 x N) = A @ BT^T + bias ----------------
template <int MODE, int BM>
__global__ __launch_bounds__(256) void gemm2_k(const unsigned short* __restrict__ A,
                                               const unsigned short* __restrict__ BT,
                                               const float* __restrict__ b0,
                                               const float* __restrict__ b1,
                                               const float* __restrict__ b2,
                                               float* __restrict__ outF,
                                               unsigned short* __restrict__ oq,
                                               unsigned short* __restrict__ ok,
                                               unsigned short* __restrict__ ov) {
  constexpr int MI = BM / 32;
  __shared__ unsigned short aS[2][BM * 32];
  __shared__ unsigned short bS[2][128 * 32];
  const int t = threadIdx.x;
  const int lane = t & 63, ln = lane & 15, g = lane >> 4;
  const int w = t >> 6, wm = w >> 1, wn = w & 1;
  const int bn0 = blockIdx.x * 128, bm0 = blockIdx.y * BM;
  f32x4 acc[MI][4] = {};

  auto stage = [&](int ks, int buf) {
    const int kk = ks * 32;
#pragma unroll
    for (int q = 0; q < BM / 64; ++q) {
      int e = q * 256 + t;
      int row = e >> 2, c8 = e & 3;
      gl2lds16(A + (size_t)(bm0 + row) * 1024 + kk + c8 * 8, &aS[buf][e * 8]);
    }
#pragma unroll
    for (int q = 0; q < 2; ++q) {
      int e = q * 256 + t;
      int row = e >> 2, c8 = e & 3;
      gl2lds16(BT + (size_t)(bn0 + row) * 1024 + kk + c8 * 8, &bS[buf][e * 8]);
    }
  };

  stage(0, 0);
  for (int ks = 0; ks < 32; ++ks) {
    const int buf = ks & 1;
    __syncthreads();
    if (ks + 1 < 32) stage(ks + 1, buf ^ 1);
    bf16x8 af[MI], bfv[4];
#pragma unroll
    for (int i = 0; i < MI; ++i)
      af[i] = bc8(*(const s16x8*)&aS[buf][(wm * (BM / 2) + i * 16 + ln) * 32 + g * 8]);
#pragma unroll
    for (int i = 0; i < 4; ++i)
      bfv[i] = bc8(*(const s16x8*)&bS[buf][(wn * 64 + i * 16 + ln) * 32 + g * 8]);
#pragma unroll
    for (int mi = 0; mi < MI; ++mi)
#pragma unroll
      for (int ni = 0; ni < 4; ++ni)
        acc[mi][ni] = __builtin_amdgcn_mfma_f32_16x16x32_bf16(af[mi], bfv[ni], acc[mi][ni], 0, 0, 0);
  }

#pragma unroll
  for (int ni = 0; ni < 4; ++ni) {
    const int n = bn0 + wn * 64 + ni * 16 + ln;
    const int n1 = n & 1023;
    const float* bp = (MODE == 2) ? b0 : (n < 1024 ? b0 : (n < 2048 ? b1 : b2));
    const float bias = bp[n1];
#pragma unroll
    for (int mi = 0; mi < MI; ++mi)
#pragma unroll
      for (int r = 0; r < 4; ++r) {
        const int m = bm0 + wm * (BM / 2) + mi * 16 + g * 4 + r;
        const float v = acc[mi][ni][r] + bias;
        if (MODE == 2) {
          outF[(size_t)m * 1024 + n] = v;
        } else {
          const int ix = trans_ix(m, n1);
          if (n < 1024) {
            oq[ix] = f2bf(v * 0.125f);
          } else if (n < 2048) {
            ok[ix] = f2bf(v);
            outF[4194304 + ix] = v;
          } else {
            ov[ix] = f2bf(v);
            outF[8388608 + ix] = v;
          }
        }
      }
  }
}

// ---------------- flash attention v4: 32x32 MFMA, in-register P ----------------
// S^T = mfma32(K, Q): lane l owns q = l&31 (partner l^32 holds other kv offsets).
// O^T = mfma32(V^T, P). P exchanged lane<->lane^32 via v_permlane32_swap_b32 (VALU).
// K/V in XOR-swizzled LDS (128B rows, slot' = slot ^ (row&7)), double-buffered.
// Block: 4 waves x 32 q = 128 q-rows; does q-tiles {i, 15-i} sequentially -> 34
// equal units/block, 256 blocks (1/CU), bh%8 == wg%8 for XCD/L2 locality.
__global__ __launch_bounds__(256) void attn_k(const unsigned short* __restrict__ qb,
                                              const unsigned short* __restrict__ kb,
                                              const unsigned short* __restrict__ vb,
                                              unsigned short* __restrict__ ob) {
  __shared__ s16x8 kS[2][512];  // [buf][kv*8 + slot'] 64 rows x 128B
  __shared__ s16x8 vS[2][512];  // [buf][dh*8 + slot'] V transposed
  const int t = threadIdx.x;
  const int lane = t & 63, l31 = lane & 31, h5 = lane >> 5;
  const int w = t >> 6;
  const unsigned wg = blockIdx.x;
  const int x = wg & 7, p = wg >> 3;
  const int bh = x + 8 * (p & 3);
  const int pairidx = p >> 2;  // 0..7
  const int b = bh >> 4, h = bh & 15;
  const unsigned short* Qp = qb + (size_t)bh * 131072;
  const unsigned short* Kp = kb + (size_t)bh * 131072;
  const unsigned short* Vp = vb + (size_t)bh * 131072;

  const int krow = t >> 2, kseg = t & 3;   // K stage: row 0..63, 2 slots
  const int dhb = t >> 4, kvb_ = t & 15;   // V stage: dh-block, kv-block

  for (int half = 0; half < 2; ++half) {
    const int qblk = half == 0 ? pairidx : 15 - pairidx;
    const int q0 = qblk * 128;
    const int ntile = 2 * qblk + 2;
    const int qg = q0 + w * 32 + l31;

    bf16x8 qf[4];
#pragma unroll
    for (int m = 0; m < 4; ++m)
      qf[m] = bc8(*(const s16x8*)(Qp + (size_t)qg * 64 + 16 * m + 8 * h5));

    f32x16 o0 = {}, o1 = {};
    float mrow = -1e30f, lrow = 0.f;

    __syncthreads();  // previous half's readers done
    {  // prologue: stage tile 0 -> buf 0
      const s16x8* ks = (const s16x8*)(Kp + krow * 64 + kseg * 16);
      s16x8 k0 = ks[0], k1 = ks[1];
      kS[0][krow * 8 + ((2 * kseg) ^ (krow & 7))]     = k0;
      kS[0][krow * 8 + ((2 * kseg + 1) ^ (krow & 7))] = k1;
      s16x4 vj[4];
#pragma unroll
      for (int j = 0; j < 4; ++j)
        vj[j] = *(const s16x4*)(Vp + (kvb_ * 4 + j) * 64 + dhb * 4);
      short* vbase = (short*)&vS[0][0];
#pragma unroll
      for (int d = 0; d < 4; ++d) {
        const int row = dhb * 4 + d;
        s16x4 wv;
        wv[0] = vj[0][d]; wv[1] = vj[1][d]; wv[2] = vj[2][d]; wv[3] = vj[3][d];
        *(s16x4*)(vbase + row * 64 + ((kvb_ >> 1) ^ (row & 7)) * 8 + (kvb_ & 1) * 4) = wv;
      }
    }
    __syncthreads();

    for (int tile = 0; tile < ntile; ++tile) {
      const int buf = tile & 1;
      const bool pre = (tile + 1) < ntile;
      s16x8 pk0, pk1;
      s16x4 pvj[4];
      if (pre) {  // issue next tile's global loads early
        const int kv1 = (tile + 1) * 64;
        const s16x8* ks = (const s16x8*)(Kp + (kv1 + krow) * 64 + kseg * 16);
        pk0 = ks[0];
        pk1 = ks[1];
#pragma unroll
        for (int j = 0; j < 4; ++j)
          pvj[j] = *(const s16x4*)(Vp + (kv1 + kvb_ * 4 + j) * 64 + dhb * 4);
      }

      const bool active = (tile * 64 <= q0 + w * 32 + 31);  // wave-uniform
      if (active) {
        // ---- S^T = K Q^T ----
        f32x16 s0 = {}, s1 = {};
        const s16x8* kb_ = &kS[buf][0];
#pragma unroll
        for (int m = 0; m < 4; ++m) {
          const int sl = 2 * m + h5;
          bf16x8 a0 = bc8(kb_[l31 * 8 + (sl ^ (l31 & 7))]);
          bf16x8 a1 = bc8(kb_[(l31 + 32) * 8 + (sl ^ (l31 & 7))]);
          s0 = mfma32(a0, qf[m], s0);
          s1 = mfma32(a1, qf[m], s1);
        }
        // causal mask
        if (tile * 64 + 63 > q0 + w * 32) {
#pragma unroll
          for (int r = 0; r < 16; ++r) {
            const int kvr = tile * 64 + (r & 3) + 8 * (r >> 2) + 4 * h5;
            if (kvr > qg) s0[r] = -1e30f;
            if (kvr + 32 > qg) s1[r] = -1e30f;
          }
        }
        // ---- online softmax (row q = l31; partner lane^32) ----
        float mt = -1e30f;
#pragma unroll
        for (int r = 0; r < 16; ++r) mt = fmaxf(mt, fmaxf(s0[r], s1[r]));
        mt = fmaxf(mt, __shfl_xor(mt, 32));
        const float mn = fmaxf(mrow, mt);
        const float alpha = __expf(mrow - mn);
        float ps = 0.f;
#pragma unroll
        for (int r = 0; r < 16; ++r) {
          s0[r] = __expf(s0[r] - mn);
          s1[r] = __expf(s1[r] - mn);
          ps += s0[r] + s1[r];
        }
        ps += __shfl_xor(ps, 32);
        lrow = lrow * alpha + ps;
        mrow = mn;
#pragma unroll
        for (int r = 0; r < 16; ++r) { o0[r] *= alpha; o1[r] *= alpha; }

        // ---- pack P to bf16 groups: og[tau][g][wd], g covers kv 8g+4*h5..+3 ----
        unsigned og[2][4][2];
#pragma unroll
        for (int g = 0; g < 4; ++g) {
          og[0][g][0] = pack2(s0[4 * g], s0[4 * g + 1]);
          og[0][g][1] = pack2(s0[4 * g + 2], s0[4 * g + 3]);
          og[1][g][0] = pack2(s1[4 * g], s1[4 * g + 1]);
          og[1][g][1] = pack2(s1[4 * g + 2], s1[4 * g + 3]);
        }
        // ---- exchange halves -> PV B-frags: frag[m'] = {X0,X1,Y0,Y1} ----
        bf16x8 pf[4];
#pragma unroll
        for (int mp = 0; mp < 4; ++mp) {
          const int tau = mp >> 1, lc = mp & 1;
          unsigned a0 = og[tau][2 * lc][0], b0 = og[tau][2 * lc + 1][0];
          unsigned a1 = og[tau][2 * lc][1], b1 = og[tau][2 * lc + 1][1];
          asm volatile("v_permlane32_swap_b32 %0, %1" : "+v"(a0), "+v"(b0));
          asm volatile("v_permlane32_swap_b32 %0, %1" : "+v"(a1), "+v"(b1));
          u32x4 fw; fw[0] = a0; fw[1] = a1; fw[2] = b0; fw[3] = b1;
          pf[mp] = __builtin_bit_cast(bf16x8, fw);
        }
        // ---- O^T += V^T P ----
        const s16x8* vb2 = &vS[buf][0];
#pragma unroll
        for (int mp = 0; mp < 4; ++mp) {
          const int sl = 2 * mp + h5;
          bf16x8 va0 = bc8(vb2[l31 * 8 + (sl ^ (l31 & 7))]);
          bf16x8 va1 = bc8(vb2[(l31 + 32) * 8 + (sl ^ (l31 & 7))]);
          o0 = mfma32(va0, pf[mp], o0);
          o1 = mfma32(va1, pf[mp], o1);
        }
      }

      if (pre) {  // write prefetched tile into other buffer
        const int ob_ = buf ^ 1;
        kS[ob_][krow * 8 + ((2 * kseg) ^ (krow & 7))]     = pk0;
        kS[ob_][krow * 8 + ((2 * kseg + 1) ^ (krow & 7))] = pk1;
        short* vbase = (short*)&vS[ob_][0];
#pragma unroll
        for (int d = 0; d < 4; ++d) {
          const int row = dhb * 4 + d;
          s16x4 wv;
          wv[0] = pvj[0][d]; wv[1] = pvj[1][d]; wv[2] = pvj[2][d]; wv[3] = pvj[3][d];
          *(s16x4*)(vbase + row * 64 + ((kvb_ >> 1) ^ (row & 7)) * 8 + (kvb_ & 1) * 4) = wv;
        }
        __syncthreads();
      }
    }

    // ---- epilogue: o{0,1}[r] = O^T[dh = 32*sigma + (r&3)+8*(r>>2)+4*h5][q = qg] ----
    const float inv = 1.0f / lrow;
    unsigned short* orow = ob + (size_t)(b * 2048 + qg) * 1024 + h * 64;
#pragma unroll
    for (int rq = 0; rq < 4; ++rq) {
      s16x4 ov0, ov1;
#pragma unroll
      for (int e = 0; e < 4; ++e) {
        ov0[e] = (short)f2bf(o0[4 * rq + e] * inv);
        ov1[e] = (short)f2bf(o1[4 * rq + e] * inv);
      }
      *(s16x4*)(orow + 8 * rq + 4 * h5)      = ov0;
      *(s16x4*)(orow + 32 + 8 * rq + 4 * h5) = ov1;
    }
  }
}

extern "C" void kernel_launch(void* const* d_in, const int* in_sizes, int n_in,
                              void* d_out, int out_size, void* d_ws, size_t ws_size,
                              hipStream_t stream) {
  (void)in_sizes; (void)n_in; (void)out_size; (void)ws_size;
  const float* x  = (const float*)d_in[0];
  const float* Wq = (const float*)d_in[1];
  const float* bq = (const float*)d_in[2];
  const float* Wk = (const float*)d_in[3];
  const float* bk = (const float*)d_in[4];
  const float* Wv = (const float*)d_in[5];
  const float* bv = (const float*)d_in[6];
  const float* Wo = (const float*)d_in[7];
  const float* bo = (const float*)d_in[8];
  float* out = (float*)d_out;

  unsigned short* ws  = (unsigned short*)d_ws;
  unsigned short* xb  = ws;
  unsigned short* wtb = ws + 4194304;
  unsigned short* qbuf = ws + 8388608;
  unsigned short* kbuf = qbuf + 4194304;
  unsigned short* vbuf = kbuf + 4194304;
  unsigned short* ab   = vbuf + 4194304;

  cast_x_k<<<2048, 256, 0, stream>>>(x, xb);
  transpose_w_k<<<dim3(16, 16, 4), 256, 0, stream>>>(Wq, Wk, Wv, Wo, wtb);
  gemm2_k<0, 128><<<dim3(24, 32), 256, 0, stream>>>(xb, wtb, bq, bk, bv, out, qbuf, kbuf, vbuf);
  attn_k<<<256, 256, 0, stream>>>(qbuf, kbuf, vbuf, ab);
  gemm2_k<2, 64><<<dim3(8, 64), 256, 0, stream>>>(ab, wtb + 3145728, bo, bo, bo, out,
                                                  nullptr, nullptr, nullptr);
}

// Round 6
// 127.955 us; speedup vs baseline: 1.2090x; 1.2090x over previous
//
#include <hip/hip_runtime.h>

typedef float  f32x4  __attribute__((ext_vector_type(4)));
typedef float  f32x16 __attribute__((ext_vector_type(16)));
typedef __bf16 bf16x8 __attribute__((ext_vector_type(8)));
typedef short  s16x8  __attribute__((ext_vector_type(8)));
typedef short  s16x4  __attribute__((ext_vector_type(4)));
typedef unsigned int u32x4 __attribute__((ext_vector_type(4)));

static __device__ __forceinline__ unsigned short f2bf(float f) {
  return __builtin_bit_cast(unsigned short, (__bf16)f);
}
static __device__ __forceinline__ bf16x8 bc8(s16x8 v) {
  return __builtin_bit_cast(bf16x8, v);
}
static __device__ __forceinline__ f32x16 mfma32(bf16x8 a, bf16x8 b, f32x16 c) {
  return __builtin_amdgcn_mfma_f32_32x32x16_bf16(a, b, c, 0, 0, 0);
}
static __device__ __forceinline__ unsigned pack2(float a, float b) {
  return ((unsigned)f2bf(b) << 16) | f2bf(a);
}

// async global->LDS, 16B per lane.
static __device__ __forceinline__ void gl2lds16(const unsigned short* g, unsigned short* l) {
  __builtin_amdgcn_global_load_lds(
      (const __attribute__((address_space(1))) unsigned int*)g,
      (__attribute__((address_space(3))) unsigned int*)l, 16, 0, 0);
}

// ---------------- cast x (fp32 -> bf16) ----------------
__global__ void cast_x_k(const float* __restrict__ x, unsigned short* __restrict__ xb) {
  int i = (blockIdx.x * 256 + threadIdx.x) * 8;
  float4 a = *(const float4*)(x + i);
  float4 b = *(const float4*)(x + i + 4);
  s16x8 o;
  o[0] = (short)f2bf(a.x); o[1] = (short)f2bf(a.y);
  o[2] = (short)f2bf(a.z); o[3] = (short)f2bf(a.w);
  o[4] = (short)f2bf(b.x); o[5] = (short)f2bf(b.y);
  o[6] = (short)f2bf(b.z); o[7] = (short)f2bf(b.w);
  *(s16x8*)(xb + i) = o;
}

// ------------- transpose W (1024x1024 fp32 k-major) -> WT bf16 (n-major) -------------
__global__ void transpose_w_k(const float* __restrict__ W0, const float* __restrict__ W1,
                              const float* __restrict__ W2, const float* __restrict__ W3,
                              unsigned short* __restrict__ wtb) {
  const float* W = blockIdx.z == 0 ? W0 : blockIdx.z == 1 ? W1 : blockIdx.z == 2 ? W2 : W3;
  unsigned short* out = wtb + (size_t)blockIdx.z * 1048576;
  __shared__ unsigned short tl[64][72];
  const int t = threadIdx.x;
  const int kt = blockIdx.y * 64, nt = blockIdx.x * 64;
  const int row = t >> 2, seg = t & 3;
  const float* src = W + (kt + row) * 1024 + nt + seg * 16;
#pragma unroll
  for (int q = 0; q < 4; ++q) {
    float4 v = *(const float4*)(src + q * 4);
    tl[seg * 16 + q * 4 + 0][row] = f2bf(v.x);
    tl[seg * 16 + q * 4 + 1][row] = f2bf(v.y);
    tl[seg * 16 + q * 4 + 2][row] = f2bf(v.z);
    tl[seg * 16 + q * 4 + 3][row] = f2bf(v.w);
  }
  __syncthreads();
  unsigned short* dst = out + (nt + row) * 1024 + kt + seg * 16;
  *(s16x8*)dst       = *(const s16x8*)&tl[row][seg * 16];
  *(s16x8*)(dst + 8) = *(const s16x8*)&tl[row][seg * 16 + 8];
}

static __device__ __forceinline__ int trans_ix(int m, int n) {
  int b = m >> 11, tt = m & 2047, h = n >> 6, dh = n & 63;
  return ((b << 4) + h) * 131072 + tt * 64 + dh;
}

// ---------------- GEMM (m97 structure): C(4096 x N) = A @ BT^T + bias ----------------
template <int MODE, int BM>
__global__ __launch_bounds__(256) void gemm2_k(const unsigned short* __restrict__ A,
                                               const unsigned short* __restrict__ BT,
                                               const float* __restrict__ b0,
                                               const float* __restrict__ b1,
                                               const float* __restrict__ b2,
                                               float* __restrict__ outF,
                                               unsigned short* __restrict__ oq,
                                               unsigned short* __restrict__ ok,
                                               unsigned short* __restrict__ ov) {
  constexpr int MI = BM / 32;
  __shared__ unsigned short aS[2][BM * 32];
  __shared__ unsigned short bS[2][128 * 32];
  const int t = threadIdx.x;
  const int lane = t & 63, ln = lane & 15, g = lane >> 4;
  const int w = t >> 6, wm = w >> 1, wn = w & 1;
  const int bn0 = blockIdx.x * 128, bm0 = blockIdx.y * BM;
  f32x4 acc[MI][4] = {};

  auto stage = [&](int ks, int buf) {
    const int kk = ks * 32;
#pragma unroll
    for (int q = 0; q < BM / 64; ++q) {
      int e = q * 256 + t;
      int row = e >> 2, c8 = e & 3;
      gl2lds16(A + (size_t)(bm0 + row) * 1024 + kk + c8 * 8, &aS[buf][e * 8]);
    }
#pragma unroll
    for (int q = 0; q < 2; ++q) {
      int e = q * 256 + t;
      int row = e >> 2, c8 = e & 3;
      gl2lds16(BT + (size_t)(bn0 + row) * 1024 + kk + c8 * 8, &bS[buf][e * 8]);
    }
  };

  stage(0, 0);
  for (int ks = 0; ks < 32; ++ks) {
    const int buf = ks & 1;
    __syncthreads();
    if (ks + 1 < 32) stage(ks + 1, buf ^ 1);
    bf16x8 af[MI], bfv[4];
#pragma unroll
    for (int i = 0; i < MI; ++i)
      af[i] = bc8(*(const s16x8*)&aS[buf][(wm * (BM / 2) + i * 16 + ln) * 32 + g * 8]);
#pragma unroll
    for (int i = 0; i < 4; ++i)
      bfv[i] = bc8(*(const s16x8*)&bS[buf][(wn * 64 + i * 16 + ln) * 32 + g * 8]);
#pragma unroll
    for (int mi = 0; mi < MI; ++mi)
#pragma unroll
      for (int ni = 0; ni < 4; ++ni)
        acc[mi][ni] = __builtin_amdgcn_mfma_f32_16x16x32_bf16(af[mi], bfv[ni], acc[mi][ni], 0, 0, 0);
  }

#pragma unroll
  for (int ni = 0; ni < 4; ++ni) {
    const int n = bn0 + wn * 64 + ni * 16 + ln;
    const int n1 = n & 1023;
    const float* bp = (MODE == 2) ? b0 : (n < 1024 ? b0 : (n < 2048 ? b1 : b2));
    const float bias = bp[n1];
#pragma unroll
    for (int mi = 0; mi < MI; ++mi)
#pragma unroll
      for (int r = 0; r < 4; ++r) {
        const int m = bm0 + wm * (BM / 2) + mi * 16 + g * 4 + r;
        const float v = acc[mi][ni][r] + bias;
        if (MODE == 2) {
          outF[(size_t)m * 1024 + n] = v;
        } else {
          const int ix = trans_ix(m, n1);
          if (n < 1024) {
            oq[ix] = f2bf(v * 0.125f);
          } else if (n < 2048) {
            ok[ix] = f2bf(v);
            outF[4194304 + ix] = v;
          } else {
            ov[ix] = f2bf(v);
            outF[8388608 + ix] = v;
          }
        }
      }
  }
}

// ---------------- flash attention v5: 8 waves, kv-range split + merge ----------------
// Waves 0-3 (grp A) and 4-7 (grp B) cover the SAME 128 q-rows; grp A does kv tiles
// [0, NT), grp B [NT, 2*NT) where NT = qblk+1 (N always even -> lockstep phases).
// Inner math = r5 (verified): S^T = mfma32(K,Q), in-register P via permlane32_swap,
// O^T = mfma32(V^T,P), XOR-swizzled 128B-row K/V LDS, per-group double buffering.
// End of half: two-way online-softmax merge through LDS (scalar f32, stride 17).
// Pairs {p,15-p} -> 17 phases/block. 256 blocks, bh%8 == wg%8 XCD locality.
__global__ __launch_bounds__(512) void attn_k(const unsigned short* __restrict__ qb,
                                              const unsigned short* __restrict__ kb,
                                              const unsigned short* __restrict__ vb,
                                              unsigned short* __restrict__ ob) {
  __shared__ s16x8 kS[2][2][512];  // [grp][buf][kv*8 + slot'] 64 rows x 128B
  __shared__ s16x8 vS[2][2][512];  // [grp][buf][dh*8 + slot'] V transposed
  const int t = threadIdx.x;
  const int lane = t & 63, l31 = lane & 31, h5 = lane >> 5;
  const int w = t >> 6, grp = w >> 2, qw = w & 3;
  const unsigned wg = blockIdx.x;
  const int x = wg & 7, r_ = wg >> 3;
  const int bh = x + 8 * (r_ >> 3);
  const int p = r_ & 7;
  const int b = bh >> 4, h = bh & 15;
  const unsigned short* Qp = qb + (size_t)bh * 131072;
  const unsigned short* Kp = kb + (size_t)bh * 131072;
  const unsigned short* Vp = vb + (size_t)bh * 131072;

  const int tp = t & 255;                    // per-group staging thread id
  const int krow = tp >> 2, kseg = tp & 3;   // K stage: row, 2 slots
  const int dhb = tp >> 4, kvb_ = tp & 15;   // V stage: dh-block, kv-block

  float* mg0 = (float*)&kS[0][0][0];
  float* mg1 = (float*)&vS[0][0][0];
  float* ml = mg0 + 17 * 256;
  const int slot = qw * 64 + lane;

  for (int half = 0; half < 2; ++half) {
    const int qblk = half == 0 ? p : 15 - p;
    const int q0 = qblk * 128;
    const int NT = qblk + 1;            // tiles per group
    const int tbase = grp * NT;
    const int qg = q0 + qw * 32 + l31;

    bf16x8 qf[4];
#pragma unroll
    for (int m = 0; m < 4; ++m)
      qf[m] = bc8(*(const s16x8*)(Qp + (size_t)qg * 64 + 16 * m + 8 * h5));

    f32x16 o0 = {}, o1 = {};
    float mrow = -1e30f, lrow = 0.f;

    __syncthreads();  // previous half's LDS users done
    {  // prologue: stage group's tile 0 -> buf 0
      const int kv0 = tbase * 64;
      const s16x8* ks = (const s16x8*)(Kp + (kv0 + krow) * 64 + kseg * 16);
      s16x8 k0 = ks[0], k1 = ks[1];
      kS[grp][0][krow * 8 + ((2 * kseg) ^ (krow & 7))]     = k0;
      kS[grp][0][krow * 8 + ((2 * kseg + 1) ^ (krow & 7))] = k1;
      s16x4 vj[4];
#pragma unroll
      for (int j = 0; j < 4; ++j)
        vj[j] = *(const s16x4*)(Vp + (kv0 + kvb_ * 4 + j) * 64 + dhb * 4);
      short* vbase = (short*)&vS[grp][0][0];
#pragma unroll
      for (int dd = 0; dd < 4; ++dd) {
        const int d = (dd + dhb) & 3;
        const int row = dhb * 4 + d;
        s16x4 wv;
        wv[0] = vj[0][d]; wv[1] = vj[1][d]; wv[2] = vj[2][d]; wv[3] = vj[3][d];
        *(s16x4*)(vbase + row * 64 + ((kvb_ >> 1) ^ (row & 7)) * 8 + (kvb_ & 1) * 4) = wv;
      }
    }
    __syncthreads();

    for (int i = 0; i < NT; ++i) {
      const int buf = i & 1;
      const bool pre = (i + 1) < NT;
      const int kv0 = (tbase + i) * 64;
      s16x8 pk0, pk1;
      s16x4 pvj[4];
      if (pre) {  // issue next tile's global loads early
        const int kv1 = kv0 + 64;
        const s16x8* ks = (const s16x8*)(Kp + (kv1 + krow) * 64 + kseg * 16);
        pk0 = ks[0];
        pk1 = ks[1];
#pragma unroll
        for (int j = 0; j < 4; ++j)
          pvj[j] = *(const s16x4*)(Vp + (kv1 + kvb_ * 4 + j) * 64 + dhb * 4);
      }

      const bool active = (kv0 <= q0 + qw * 32 + 31);  // wave-uniform
      if (active) {
        // ---- S^T = K Q^T ----
        f32x16 s0 = {}, s1 = {};
        const s16x8* kb_ = &kS[grp][buf][0];
#pragma unroll
        for (int m = 0; m < 4; ++m) {
          const int sl = 2 * m + h5;
          bf16x8 a0 = bc8(kb_[l31 * 8 + (sl ^ (l31 & 7))]);
          bf16x8 a1 = bc8(kb_[(l31 + 32) * 8 + (sl ^ (l31 & 7))]);
          s0 = mfma32(a0, qf[m], s0);
          s1 = mfma32(a1, qf[m], s1);
        }
        // causal mask
        if (kv0 + 63 > q0 + qw * 32) {
#pragma unroll
          for (int r = 0; r < 16; ++r) {
            const int kvr = kv0 + (r & 3) + 8 * (r >> 2) + 4 * h5;
            if (kvr > qg) s0[r] = -1e30f;
            if (kvr + 32 > qg) s1[r] = -1e30f;
          }
        }
        // ---- online softmax (row q = l31; partner lane^32) ----
        float mt = -1e30f;
#pragma unroll
        for (int r = 0; r < 16; ++r) mt = fmaxf(mt, fmaxf(s0[r], s1[r]));
        mt = fmaxf(mt, __shfl_xor(mt, 32));
        const float mn = fmaxf(mrow, mt);
        const float alpha = __expf(mrow - mn);
        float ps = 0.f;
#pragma unroll
        for (int r = 0; r < 16; ++r) {
          s0[r] = __expf(s0[r] - mn);
          s1[r] = __expf(s1[r] - mn);
          ps += s0[r] + s1[r];
        }
        ps += __shfl_xor(ps, 32);
        lrow = lrow * alpha + ps;
        mrow = mn;
#pragma unroll
        for (int r = 0; r < 16; ++r) { o0[r] *= alpha; o1[r] *= alpha; }

        // ---- pack P to bf16, exchange halves via permlane32_swap ----
        unsigned og[2][4][2];
#pragma unroll
        for (int g = 0; g < 4; ++g) {
          og[0][g][0] = pack2(s0[4 * g], s0[4 * g + 1]);
          og[0][g][1] = pack2(s0[4 * g + 2], s0[4 * g + 3]);
          og[1][g][0] = pack2(s1[4 * g], s1[4 * g + 1]);
          og[1][g][1] = pack2(s1[4 * g + 2], s1[4 * g + 3]);
        }
        bf16x8 pf[4];
#pragma unroll
        for (int mp = 0; mp < 4; ++mp) {
          const int tau = mp >> 1, lc = mp & 1;
          unsigned a0 = og[tau][2 * lc][0], b0 = og[tau][2 * lc + 1][0];
          unsigned a1 = og[tau][2 * lc][1], b1 = og[tau][2 * lc + 1][1];
          asm volatile("v_permlane32_swap_b32 %0, %1" : "+v"(a0), "+v"(b0));
          asm volatile("v_permlane32_swap_b32 %0, %1" : "+v"(a1), "+v"(b1));
          u32x4 fw; fw[0] = a0; fw[1] = a1; fw[2] = b0; fw[3] = b1;
          pf[mp] = __builtin_bit_cast(bf16x8, fw);
        }
        // ---- O^T += V^T P ----
        const s16x8* vb2 = &vS[grp][buf][0];
#pragma unroll
        for (int mp = 0; mp < 4; ++mp) {
          const int sl = 2 * mp + h5;
          bf16x8 va0 = bc8(vb2[l31 * 8 + (sl ^ (l31 & 7))]);
          bf16x8 va1 = bc8(vb2[(l31 + 32) * 8 + (sl ^ (l31 & 7))]);
          o0 = mfma32(va0, pf[mp], o0);
          o1 = mfma32(va1, pf[mp], o1);
        }
      }

      if (pre) {  // write prefetched tile into other buffer
        const int ob_ = buf ^ 1;
        kS[grp][ob_][krow * 8 + ((2 * kseg) ^ (krow & 7))]     = pk0;
        kS[grp][ob_][krow * 8 + ((2 * kseg + 1) ^ (krow & 7))] = pk1;
        short* vbase = (short*)&vS[grp][ob_][0];
#pragma unroll
        for (int dd = 0; dd < 4; ++dd) {
          const int d = (dd + dhb) & 3;
          const int row = dhb * 4 + d;
          s16x4 wv;
          wv[0] = pvj[0][d]; wv[1] = pvj[1][d]; wv[2] = pvj[2][d]; wv[3] = pvj[3][d];
          *(s16x4*)(vbase + row * 64 + ((kvb_ >> 1) ^ (row & 7)) * 8 + (kvb_ & 1) * 4) = wv;
        }
        __syncthreads();
      }
    }

    // ---- merge group B into group A ----
    __syncthreads();  // all compute done; LDS buffers free for scratch
    if (grp == 1) {
#pragma unroll
      for (int r = 0; r < 16; ++r) mg0[slot * 17 + r] = o0[r];
#pragma unroll
      for (int r = 0; r < 16; ++r) mg1[slot * 17 + r] = o1[r];
      ml[slot * 2] = mrow;
      ml[slot * 2 + 1] = lrow;
    }
    __syncthreads();
    if (grp == 0) {
      const float mb_ = ml[slot * 2], lb_ = ml[slot * 2 + 1];
      const float mstar = fmaxf(mrow, mb_);
      const float aA = __expf(mrow - mstar);
      const float aB = __expf(mb_ - mstar);
      const float inv = 1.0f / (lrow * aA + lb_ * aB);
      unsigned short* orow = ob + (size_t)(b * 2048 + qg) * 1024 + h * 64;
#pragma unroll
      for (int rq = 0; rq < 4; ++rq) {
        s16x4 ov0, ov1;
#pragma unroll
        for (int e = 0; e < 4; ++e) {
          ov0[e] = (short)f2bf((o0[4 * rq + e] * aA + mg0[slot * 17 + 4 * rq + e] * aB) * inv);
          ov1[e] = (short)f2bf((o1[4 * rq + e] * aA + mg1[slot * 17 + 4 * rq + e] * aB) * inv);
        }
        *(s16x4*)(orow + 8 * rq + 4 * h5)      = ov0;
        *(s16x4*)(orow + 32 + 8 * rq + 4 * h5) = ov1;
      }
    }
  }
}

extern "C" void kernel_launch(void* const* d_in, const int* in_sizes, int n_in,
                              void* d_out, int out_size, void* d_ws, size_t ws_size,
                              hipStream_t stream) {
  (void)in_sizes; (void)n_in; (void)out_size; (void)ws_size;
  const float* x  = (const float*)d_in[0];
  const float* Wq = (const float*)d_in[1];
  const float* bq = (const float*)d_in[2];
  const float* Wk = (const float*)d_in[3];
  const float* bk = (const float*)d_in[4];
  const float* Wv = (const float*)d_in[5];
  const float* bv = (const float*)d_in[6];
  const float* Wo = (const float*)d_in[7];
  const float* bo = (const float*)d_in[8];
  float* out = (float*)d_out;

  unsigned short* ws  = (unsigned short*)d_ws;
  unsigned short* xb  = ws;
  unsigned short* wtb = ws + 4194304;
  unsigned short* qbuf = ws + 8388608;
  unsigned short* kbuf = qbuf + 4194304;
  unsigned short* vbuf = kbuf + 4194304;
  unsigned short* ab   = vbuf + 4194304;

  cast_x_k<<<2048, 256, 0, stream>>>(x, xb);
  transpose_w_k<<<dim3(16, 16, 4), 256, 0, stream>>>(Wq, Wk, Wv, Wo, wtb);
  gemm2_k<0, 128><<<dim3(24, 32), 256, 0, stream>>>(xb, wtb, bq, bk, bv, out, qbuf, kbuf, vbuf);
  attn_k<<<256, 512, 0, stream>>>(qbuf, kbuf, vbuf, ab);
  gemm2_k<2, 64><<<dim3(8, 64), 256, 0, stream>>>(ab, wtb + 3145728, bo, bo, bo, out,
                                                  nullptr, nullptr, nullptr);
}

// Round 7
// 120.253 us; speedup vs baseline: 1.2865x; 1.0640x over previous
//
#include <hip/hip_runtime.h>

typedef float  f32x4  __attribute__((ext_vector_type(4)));
typedef float  f32x16 __attribute__((ext_vector_type(16)));
typedef __bf16 bf16x8 __attribute__((ext_vector_type(8)));
typedef short  s16x8  __attribute__((ext_vector_type(8)));
typedef short  s16x4  __attribute__((ext_vector_type(4)));
typedef unsigned int u32x4 __attribute__((ext_vector_type(4)));

static __device__ __forceinline__ unsigned short f2bf(float f) {
  return __builtin_bit_cast(unsigned short, (__bf16)f);
}
static __device__ __forceinline__ bf16x8 bc8(s16x8 v) {
  return __builtin_bit_cast(bf16x8, v);
}
static __device__ __forceinline__ f32x16 mfma32(bf16x8 a, bf16x8 b, f32x16 c) {
  return __builtin_amdgcn_mfma_f32_32x32x16_bf16(a, b, c, 0, 0, 0);
}
static __device__ __forceinline__ f32x4 mfma16(bf16x8 a, bf16x8 b, f32x4 c) {
  return __builtin_amdgcn_mfma_f32_16x16x32_bf16(a, b, c, 0, 0, 0);
}
static __device__ __forceinline__ unsigned pack2(float a, float b) {
  return ((unsigned)f2bf(b) << 16) | f2bf(a);
}

// async global->LDS, 16B per lane.
static __device__ __forceinline__ void gl2lds16(const unsigned short* g, unsigned short* l) {
  __builtin_amdgcn_global_load_lds(
      (const __attribute__((address_space(1))) unsigned int*)g,
      (__attribute__((address_space(3))) unsigned int*)l, 16, 0, 0);
}

// counted-vmcnt sync: wait until <= N vector-mem instrs outstanding, then barrier.
#define GSYNC(NSTR)                                          \
  do {                                                       \
    __builtin_amdgcn_sched_barrier(0);                       \
    asm volatile("s_waitcnt vmcnt(" NSTR ")" ::: "memory");  \
    __builtin_amdgcn_s_barrier();                            \
    __builtin_amdgcn_sched_barrier(0);                       \
  } while (0)

// ---------------- cast x (fp32 -> bf16) ----------------
__global__ void cast_x_k(const float* __restrict__ x, unsigned short* __restrict__ xb) {
  int i = (blockIdx.x * 256 + threadIdx.x) * 8;
  float4 a = *(const float4*)(x + i);
  float4 b = *(const float4*)(x + i + 4);
  s16x8 o;
  o[0] = (short)f2bf(a.x); o[1] = (short)f2bf(a.y);
  o[2] = (short)f2bf(a.z); o[3] = (short)f2bf(a.w);
  o[4] = (short)f2bf(b.x); o[5] = (short)f2bf(b.y);
  o[6] = (short)f2bf(b.z); o[7] = (short)f2bf(b.w);
  *(s16x8*)(xb + i) = o;
}

// ------------- transpose W (1024x1024 fp32 k-major) -> WT bf16 (n-major) -------------
__global__ void transpose_w_k(const float* __restrict__ W0, const float* __restrict__ W1,
                              const float* __restrict__ W2, const float* __restrict__ W3,
                              unsigned short* __restrict__ wtb) {
  const float* W = blockIdx.z == 0 ? W0 : blockIdx.z == 1 ? W1 : blockIdx.z == 2 ? W2 : W3;
  unsigned short* out = wtb + (size_t)blockIdx.z * 1048576;
  __shared__ unsigned short tl[64][72];
  const int t = threadIdx.x;
  const int kt = blockIdx.y * 64, nt = blockIdx.x * 64;
  const int row = t >> 2, seg = t & 3;
  const float* src = W + (kt + row) * 1024 + nt + seg * 16;
#pragma unroll
  for (int q = 0; q < 4; ++q) {
    float4 v = *(const float4*)(src + q * 4);
    tl[seg * 16 + q * 4 + 0][row] = f2bf(v.x);
    tl[seg * 16 + q * 4 + 1][row] = f2bf(v.y);
    tl[seg * 16 + q * 4 + 2][row] = f2bf(v.z);
    tl[seg * 16 + q * 4 + 3][row] = f2bf(v.w);
  }
  __syncthreads();
  unsigned short* dst = out + (nt + row) * 1024 + kt + seg * 16;
  *(s16x8*)dst       = *(const s16x8*)&tl[row][seg * 16];
  *(s16x8*)(dst + 8) = *(const s16x8*)&tl[row][seg * 16 + 8];
}

static __device__ __forceinline__ int trans_ix(int m, int n) {
  int b = m >> 11, tt = m & 2047, h = n >> 6, dh = n & 63;
  return ((b << 4) + h) * 131072 + tt * 64 + dh;
}

// ======== fused QKV GEMM: 256x256 tile, BK=64, 8 waves, counted-vmcnt pipeline ========
// C(4096 x 3072) = A(bf16 4096x1024) @ BT(3072x1024)^T + bias.
// LDS (dynamic 128KB): buf b at b*32768 shorts; within: A_kh0 @0, A_kh1 @8192,
// B_kh0 @16384, B_kh1 @24576 (each 16KB = 256 rows x 32 k-shorts).
// Swizzle: physical slot sp = sd ^ ((row>>1)&3)  (slot = 16B); applied on the
// GLOBAL source for staging (gload_lds dest linear) and on the ds_read side.
// Per K-tile: 4 phases x {1 half-tile prefetch (2 gload_lds), 8 ds_read_b128,
// 16 MFMA in setprio(1)}. Syncs every 2 phases with vmcnt(4) (never drain except last).
__global__ __launch_bounds__(512, 2) void gemm_qkv_k(const unsigned short* __restrict__ A,
                                                     const unsigned short* __restrict__ BT,
                                                     const float* __restrict__ b0,
                                                     const float* __restrict__ b1,
                                                     const float* __restrict__ b2,
                                                     float* __restrict__ outF,
                                                     unsigned short* __restrict__ oq,
                                                     unsigned short* __restrict__ ok,
                                                     unsigned short* __restrict__ ov) {
  extern __shared__ unsigned short lds[];
  const int t = threadIdx.x;
  const int lane = t & 63, ln = lane & 15, g = lane >> 4;
  const int w = t >> 6, wm = w >> 2, wn = w & 3;  // 2 (M) x 4 (N) waves
  const unsigned wgid = blockIdx.x;
  const unsigned swz = (wgid & 7) * 24 + (wgid >> 3);  // XCD-contiguous chunks (192%8==0)
  const int by = swz & 15, bx = swz >> 4;              // by fast -> share B-panels per XCD
  const int bm0 = by * 256, bn0 = bx * 256;

  // staging: thread covers (instr0: row r0, instr1: row 128+r0), slot s0; source
  // address pre-swizzled so linear LDS dest ends up swizzle-consistent with reads.
  const int r0 = t >> 2, s0v = t & 3;
  const int sd0 = s0v ^ ((r0 >> 1) & 3);
  const int r1 = 128 + r0;
  const int sd1 = s0v ^ ((r1 >> 1) & 3);
  const unsigned short* aS0 = A + (size_t)(bm0 + r0) * 1024 + sd0 * 8;
  const unsigned short* aS1 = A + (size_t)(bm0 + r1) * 1024 + sd1 * 8;
  const unsigned short* bS0 = BT + (size_t)(bn0 + r0) * 1024 + sd0 * 8;
  const unsigned short* bS1 = BT + (size_t)(bn0 + r1) * 1024 + sd1 * 8;
  const int dst = t * 8;  // shorts offset within a 16KB region (t*16B)

  auto issueA = [&](int buf, int H, int koff) {
    const int base = buf * 32768 + H * 8192;
    gl2lds16(aS0 + koff, &lds[base + dst]);
    gl2lds16(aS1 + koff, &lds[base + 4096 + dst]);
  };
  auto issueB = [&](int buf, int H, int koff) {
    const int base = buf * 32768 + 16384 + H * 8192;
    gl2lds16(bS0 + koff, &lds[base + dst]);
    gl2lds16(bS1 + koff, &lds[base + 4096 + dst]);
  };
  auto ldA = [&](int buf, int H, int mf) -> bf16x8 {
    const int row = wm * 128 + mf * 16 + ln;
    const int sp = g ^ ((row >> 1) & 3);
    return bc8(*(const s16x8*)&lds[buf * 32768 + H * 8192 + row * 32 + sp * 8]);
  };
  auto ldB = [&](int buf, int H, int nf) -> bf16x8 {
    const int row = wn * 64 + nf * 16 + ln;
    const int sp = g ^ ((row >> 1) & 3);
    return bc8(*(const s16x8*)&lds[buf * 32768 + 16384 + H * 8192 + row * 32 + sp * 8]);
  };

  f32x4 acc[8][4] = {};
  // prologue: tile 0 -> buf 0 (order matters for vmcnt accounting)
  issueA(0, 0, 0);
  issueB(0, 0, 0);
  issueA(0, 1, 32);
  issueB(0, 1, 32);

  for (int ti = 0; ti < 16; ++ti) {
    const int buf = ti & 1, nb = buf ^ 1;
    const bool hn = ti < 15;
    const int kn = (ti + 1) * 64;

    // boundary A: need tile ti kh0 (A,B) landed; tile ti kh1 (4 instrs) may remain.
    GSYNC("4");
    bf16x8 af[4], bfr[4];
    // ---- ph1: kstep0, m0..3 ----
    if (hn) issueA(nb, 0, kn);
#pragma unroll
    for (int m = 0; m < 4; ++m) af[m] = ldA(buf, 0, m);
#pragma unroll
    for (int n = 0; n < 4; ++n) bfr[n] = ldB(buf, 0, n);
    __builtin_amdgcn_s_setprio(1);
#pragma unroll
    for (int m = 0; m < 4; ++m)
#pragma unroll
      for (int n = 0; n < 4; ++n) acc[m][n] = mfma16(af[m], bfr[n], acc[m][n]);
    __builtin_amdgcn_s_setprio(0);
    // ---- ph2: kstep0, m4..7 (reuse B frags) ----
    if (hn) issueB(nb, 0, kn);
#pragma unroll
    for (int m = 0; m < 4; ++m) af[m] = ldA(buf, 0, m + 4);
    __builtin_amdgcn_s_setprio(1);
#pragma unroll
    for (int m = 0; m < 4; ++m)
#pragma unroll
      for (int n = 0; n < 4; ++n) acc[m + 4][n] = mfma16(af[m], bfr[n], acc[m + 4][n]);
    __builtin_amdgcn_s_setprio(0);

    // boundary B: need tile ti kh1 landed; (if hn) 4 new instrs may remain.
    if (hn) GSYNC("4"); else GSYNC("0");

    // ---- ph3: kstep1, m0..3 ----
    if (hn) issueA(nb, 1, kn + 32);
#pragma unroll
    for (int m = 0; m < 4; ++m) af[m] = ldA(buf, 1, m);
#pragma unroll
    for (int n = 0; n < 4; ++n) bfr[n] = ldB(buf, 1, n);
    __builtin_amdgcn_s_setprio(1);
#pragma unroll
    for (int m = 0; m < 4; ++m)
#pragma unroll
      for (int n = 0; n < 4; ++n) acc[m][n] = mfma16(af[m], bfr[n], acc[m][n]);
    __builtin_amdgcn_s_setprio(0);
    // ---- ph4: kstep1, m4..7 ----
    if (hn) issueB(nb, 1, kn + 32);
#pragma unroll
    for (int m = 0; m < 4; ++m) af[m] = ldA(buf, 1, m + 4);
    __builtin_amdgcn_s_setprio(1);
#pragma unroll
    for (int m = 0; m < 4; ++m)
#pragma unroll
      for (int n = 0; n < 4; ++n) acc[m + 4][n] = mfma16(af[m], bfr[n], acc[m + 4][n]);
    __builtin_amdgcn_s_setprio(0);
  }

  // epilogue: n-range of a block lies entirely in one of q/k/v (1024%256==0)
#pragma unroll
  for (int ni = 0; ni < 4; ++ni) {
    const int n = bn0 + wn * 64 + ni * 16 + ln;
    const int n1 = n & 1023;
    const float* bp = n < 1024 ? b0 : (n < 2048 ? b1 : b2);
    const float bias = bp[n1];
#pragma unroll
    for (int mi = 0; mi < 8; ++mi)
#pragma unroll
      for (int r = 0; r < 4; ++r) {
        const int m = bm0 + wm * 128 + mi * 16 + g * 4 + r;
        const float v = acc[mi][ni][r] + bias;
        const int ix = trans_ix(m, n1);
        if (n < 1024) {
          oq[ix] = f2bf(v * 0.125f);
        } else if (n < 2048) {
          ok[ix] = f2bf(v);
          outF[4194304 + ix] = v;
        } else {
          ov[ix] = f2bf(v);
          outF[8388608 + ix] = v;
        }
      }
  }
}

// ---------------- O-proj GEMM (m97 structure, unchanged) ----------------
template <int MODE, int BM>
__global__ __launch_bounds__(256) void gemm2_k(const unsigned short* __restrict__ A,
                                               const unsigned short* __restrict__ BT,
                                               const float* __restrict__ b0,
                                               float* __restrict__ outF) {
  constexpr int MI = BM / 32;
  __shared__ unsigned short aS[2][BM * 32];
  __shared__ unsigned short bS[2][128 * 32];
  const int t = threadIdx.x;
  const int lane = t & 63, ln = lane & 15, g = lane >> 4;
  const int w = t >> 6, wm = w >> 1, wn = w & 1;
  const int bn0 = blockIdx.x * 128, bm0 = blockIdx.y * BM;
  f32x4 acc[MI][4] = {};

  auto stage = [&](int ks, int buf) {
    const int kk = ks * 32;
#pragma unroll
    for (int q = 0; q < BM / 64; ++q) {
      int e = q * 256 + t;
      int row = e >> 2, c8 = e & 3;
      gl2lds16(A + (size_t)(bm0 + row) * 1024 + kk + c8 * 8, &aS[buf][e * 8]);
    }
#pragma unroll
    for (int q = 0; q < 2; ++q) {
      int e = q * 256 + t;
      int row = e >> 2, c8 = e & 3;
      gl2lds16(BT + (size_t)(bn0 + row) * 1024 + kk + c8 * 8, &bS[buf][e * 8]);
    }
  };

  stage(0, 0);
  for (int ks = 0; ks < 32; ++ks) {
    const int buf = ks & 1;
    __syncthreads();
    if (ks + 1 < 32) stage(ks + 1, buf ^ 1);
    bf16x8 af[MI], bfv[4];
#pragma unroll
    for (int i = 0; i < MI; ++i)
      af[i] = bc8(*(const s16x8*)&aS[buf][(wm * (BM / 2) + i * 16 + ln) * 32 + g * 8]);
#pragma unroll
    for (int i = 0; i < 4; ++i)
      bfv[i] = bc8(*(const s16x8*)&bS[buf][(wn * 64 + i * 16 + ln) * 32 + g * 8]);
#pragma unroll
    for (int mi = 0; mi < MI; ++mi)
#pragma unroll
      for (int ni = 0; ni < 4; ++ni)
        acc[mi][ni] = mfma16(af[mi], bfv[ni], acc[mi][ni]);
  }

#pragma unroll
  for (int ni = 0; ni < 4; ++ni) {
    const int n = bn0 + wn * 64 + ni * 16 + ln;
    const float bias = b0[n];
#pragma unroll
    for (int mi = 0; mi < MI; ++mi)
#pragma unroll
      for (int r = 0; r < 4; ++r) {
        const int m = bm0 + wm * (BM / 2) + mi * 16 + g * 4 + r;
        outF[(size_t)m * 1024 + n] = acc[mi][ni][r] + bias;
      }
  }
}

// ---------------- flash attention v5 (unchanged from r6) ----------------
__global__ __launch_bounds__(512) void attn_k(const unsigned short* __restrict__ qb,
                                              const unsigned short* __restrict__ kb,
                                              const unsigned short* __restrict__ vb,
                                              unsigned short* __restrict__ ob) {
  __shared__ s16x8 kS[2][2][512];
  __shared__ s16x8 vS[2][2][512];
  const int t = threadIdx.x;
  const int lane = t & 63, l31 = lane & 31, h5 = lane >> 5;
  const int w = t >> 6, grp = w >> 2, qw = w & 3;
  const unsigned wg = blockIdx.x;
  const int x = wg & 7, r_ = wg >> 3;
  const int bh = x + 8 * (r_ >> 3);
  const int p = r_ & 7;
  const int b = bh >> 4, h = bh & 15;
  const unsigned short* Qp = qb + (size_t)bh * 131072;
  const unsigned short* Kp = kb + (size_t)bh * 131072;
  const unsigned short* Vp = vb + (size_t)bh * 131072;

  const int tp = t & 255;
  const int krow = tp >> 2, kseg = tp & 3;
  const int dhb = tp >> 4, kvb_ = tp & 15;

  float* mg0 = (float*)&kS[0][0][0];
  float* mg1 = (float*)&vS[0][0][0];
  float* ml = mg0 + 17 * 256;
  const int slot = qw * 64 + lane;

  for (int half = 0; half < 2; ++half) {
    const int qblk = half == 0 ? p : 15 - p;
    const int q0 = qblk * 128;
    const int NT = qblk + 1;
    const int tbase = grp * NT;
    const int qg = q0 + qw * 32 + l31;

    bf16x8 qf[4];
#pragma unroll
    for (int m = 0; m < 4; ++m)
      qf[m] = bc8(*(const s16x8*)(Qp + (size_t)qg * 64 + 16 * m + 8 * h5));

    f32x16 o0 = {}, o1 = {};
    float mrow = -1e30f, lrow = 0.f;

    __syncthreads();
    {
      const int kv0 = tbase * 64;
      const s16x8* ks = (const s16x8*)(Kp + (kv0 + krow) * 64 + kseg * 16);
      s16x8 k0 = ks[0], k1 = ks[1];
      kS[grp][0][krow * 8 + ((2 * kseg) ^ (krow & 7))]     = k0;
      kS[grp][0][krow * 8 + ((2 * kseg + 1) ^ (krow & 7))] = k1;
      s16x4 vj[4];
#pragma unroll
      for (int j = 0; j < 4; ++j)
        vj[j] = *(const s16x4*)(Vp + (kv0 + kvb_ * 4 + j) * 64 + dhb * 4);
      short* vbase = (short*)&vS[grp][0][0];
#pragma unroll
      for (int dd = 0; dd < 4; ++dd) {
        const int d = (dd + dhb) & 3;
        const int row = dhb * 4 + d;
        s16x4 wv;
        wv[0] = vj[0][d]; wv[1] = vj[1][d]; wv[2] = vj[2][d]; wv[3] = vj[3][d];
        *(s16x4*)(vbase + row * 64 + ((kvb_ >> 1) ^ (row & 7)) * 8 + (kvb_ & 1) * 4) = wv;
      }
    }
    __syncthreads();

    for (int i = 0; i < NT; ++i) {
      const int buf = i & 1;
      const bool pre = (i + 1) < NT;
      const int kv0 = (tbase + i) * 64;
      s16x8 pk0, pk1;
      s16x4 pvj[4];
      if (pre) {
        const int kv1 = kv0 + 64;
        const s16x8* ks = (const s16x8*)(Kp + (kv1 + krow) * 64 + kseg * 16);
        pk0 = ks[0];
        pk1 = ks[1];
#pragma unroll
        for (int j = 0; j < 4; ++j)
          pvj[j] = *(const s16x4*)(Vp + (kv1 + kvb_ * 4 + j) * 64 + dhb * 4);
      }

      const bool active = (kv0 <= q0 + qw * 32 + 31);
      if (active) {
        f32x16 s0 = {}, s1 = {};
        const s16x8* kb_ = &kS[grp][buf][0];
#pragma unroll
        for (int m = 0; m < 4; ++m) {
          const int sl = 2 * m + h5;
          bf16x8 a0 = bc8(kb_[l31 * 8 + (sl ^ (l31 & 7))]);
          bf16x8 a1 = bc8(kb_[(l31 + 32) * 8 + (sl ^ (l31 & 7))]);
          s0 = mfma32(a0, qf[m], s0);
          s1 = mfma32(a1, qf[m], s1);
        }
        if (kv0 + 63 > q0 + qw * 32) {
#pragma unroll
          for (int r = 0; r < 16; ++r) {
            const int kvr = kv0 + (r & 3) + 8 * (r >> 2) + 4 * h5;
            if (kvr > qg) s0[r] = -1e30f;
            if (kvr + 32 > qg) s1[r] = -1e30f;
          }
        }
        float mt = -1e30f;
#pragma unroll
        for (int r = 0; r < 16; ++r) mt = fmaxf(mt, fmaxf(s0[r], s1[r]));
        mt = fmaxf(mt, __shfl_xor(mt, 32));
        const float mn = fmaxf(mrow, mt);
        const float alpha = __expf(mrow - mn);
        float ps = 0.f;
#pragma unroll
        for (int r = 0; r < 16; ++r) {
          s0[r] = __expf(s0[r] - mn);
          s1[r] = __expf(s1[r] - mn);
          ps += s0[r] + s1[r];
        }
        ps += __shfl_xor(ps, 32);
        lrow = lrow * alpha + ps;
        mrow = mn;
#pragma unroll
        for (int r = 0; r < 16; ++r) { o0[r] *= alpha; o1[r] *= alpha; }

        unsigned og[2][4][2];
#pragma unroll
        for (int gg = 0; gg < 4; ++gg) {
          og[0][gg][0] = pack2(s0[4 * gg], s0[4 * gg + 1]);
          og[0][gg][1] = pack2(s0[4 * gg + 2], s0[4 * gg + 3]);
          og[1][gg][0] = pack2(s1[4 * gg], s1[4 * gg + 1]);
          og[1][gg][1] = pack2(s1[4 * gg + 2], s1[4 * gg + 3]);
        }
        bf16x8 pf[4];
#pragma unroll
        for (int mp = 0; mp < 4; ++mp) {
          const int tau = mp >> 1, lc = mp & 1;
          unsigned a0 = og[tau][2 * lc][0], bq0 = og[tau][2 * lc + 1][0];
          unsigned a1 = og[tau][2 * lc][1], bq1 = og[tau][2 * lc + 1][1];
          asm volatile("v_permlane32_swap_b32 %0, %1" : "+v"(a0), "+v"(bq0));
          asm volatile("v_permlane32_swap_b32 %0, %1" : "+v"(a1), "+v"(bq1));
          u32x4 fw; fw[0] = a0; fw[1] = a1; fw[2] = bq0; fw[3] = bq1;
          pf[mp] = __builtin_bit_cast(bf16x8, fw);
        }
        const s16x8* vb2 = &vS[grp][buf][0];
#pragma unroll
        for (int mp = 0; mp < 4; ++mp) {
          const int sl = 2 * mp + h5;
          bf16x8 va0 = bc8(vb2[l31 * 8 + (sl ^ (l31 & 7))]);
          bf16x8 va1 = bc8(vb2[(l31 + 32) * 8 + (sl ^ (l31 & 7))]);
          o0 = mfma32(va0, pf[mp], o0);
          o1 = mfma32(va1, pf[mp], o1);
        }
      }

      if (pre) {
        const int ob_ = buf ^ 1;
        kS[grp][ob_][krow * 8 + ((2 * kseg) ^ (krow & 7))]     = pk0;
        kS[grp][ob_][krow * 8 + ((2 * kseg + 1) ^ (krow & 7))] = pk1;
        short* vbase = (short*)&vS[grp][ob_][0];
#pragma unroll
        for (int dd = 0; dd < 4; ++dd) {
          const int d = (dd + dhb) & 3;
          const int row = dhb * 4 + d;
          s16x4 wv;
          wv[0] = pvj[0][d]; wv[1] = pvj[1][d]; wv[2] = pvj[2][d]; wv[3] = pvj[3][d];
          *(s16x4*)(vbase + row * 64 + ((kvb_ >> 1) ^ (row & 7)) * 8 + (kvb_ & 1) * 4) = wv;
        }
        __syncthreads();
      }
    }

    __syncthreads();
    if (grp == 1) {
#pragma unroll
      for (int r = 0; r < 16; ++r) mg0[slot * 17 + r] = o0[r];
#pragma unroll
      for (int r = 0; r < 16; ++r) mg1[slot * 17 + r] = o1[r];
      ml[slot * 2] = mrow;
      ml[slot * 2 + 1] = lrow;
    }
    __syncthreads();
    if (grp == 0) {
      const float mb_ = ml[slot * 2], lb_ = ml[slot * 2 + 1];
      const float mstar = fmaxf(mrow, mb_);
      const float aA = __expf(mrow - mstar);
      const float aB = __expf(mb_ - mstar);
      const float inv = 1.0f / (lrow * aA + lb_ * aB);
      unsigned short* orow = ob + (size_t)(b * 2048 + qg) * 1024 + h * 64;
#pragma unroll
      for (int rq = 0; rq < 4; ++rq) {
        s16x4 ov0, ov1;
#pragma unroll
        for (int e = 0; e < 4; ++e) {
          ov0[e] = (short)f2bf((o0[4 * rq + e] * aA + mg0[slot * 17 + 4 * rq + e] * aB) * inv);
          ov1[e] = (short)f2bf((o1[4 * rq + e] * aA + mg1[slot * 17 + 4 * rq + e] * aB) * inv);
        }
        *(s16x4*)(orow + 8 * rq + 4 * h5)      = ov0;
        *(s16x4*)(orow + 32 + 8 * rq + 4 * h5) = ov1;
      }
    }
  }
}

extern "C" void kernel_launch(void* const* d_in, const int* in_sizes, int n_in,
                              void* d_out, int out_size, void* d_ws, size_t ws_size,
                              hipStream_t stream) {
  (void)in_sizes; (void)n_in; (void)out_size; (void)ws_size;
  const float* x  = (const float*)d_in[0];
  const float* Wq = (const float*)d_in[1];
  const float* bq = (const float*)d_in[2];
  const float* Wk = (const float*)d_in[3];
  const float* bk = (const float*)d_in[4];
  const float* Wv = (const float*)d_in[5];
  const float* bv = (const float*)d_in[6];
  const float* Wo = (const float*)d_in[7];
  const float* bo = (const float*)d_in[8];
  float* out = (float*)d_out;

  unsigned short* ws  = (unsigned short*)d_ws;
  unsigned short* xb  = ws;
  unsigned short* wtb = ws + 4194304;
  unsigned short* qbuf = ws + 8388608;
  unsigned short* kbuf = qbuf + 4194304;
  unsigned short* vbuf = kbuf + 4194304;
  unsigned short* ab   = vbuf + 4194304;

  cast_x_k<<<2048, 256, 0, stream>>>(x, xb);
  transpose_w_k<<<dim3(16, 16, 4), 256, 0, stream>>>(Wq, Wk, Wv, Wo, wtb);
  gemm_qkv_k<<<192, 512, 131072, stream>>>(xb, wtb, bq, bk, bv, out, qbuf, kbuf, vbuf);
  attn_k<<<256, 512, 0, stream>>>(qbuf, kbuf, vbuf, ab);
  gemm2_k<2, 64><<<dim3(8, 64), 256, 0, stream>>>(ab, wtb + 3145728, bo, out);
}